// Round 16
// baseline (262.519 us; speedup 1.0000x reference)
//
#include <hip/hip_runtime.h>
#include <hip/hip_bf16.h>
#include <math.h>

// Problem constants (fixed by the reference).
constexpr int N_I = 50000;   // interior nodes
constexpr int N_B = 2000;    // boundary nodes
constexpr int E_I = 800000;  // interior edges
constexpr int E_B = 16000;   // boundary edges
constexpr int E_T = E_I + E_B;
constexpr int NTILES = (N_I + 31) / 32;       // 1563 row-tiles (= k_mm grid)
// CSR bucket build
constexpr int NBIN = (N_I + 1023) / 1024;     // 49 bins of 1024 nodes
constexpr int EPB = 2048;                     // edges per hist/scatter block
constexpr int NB = (E_T + EPB - 1) / EPB;     // 399 blocks
constexpr int SM = NBIN * NB;                 // 19551 scan entries
constexpr int SCT = 1024;                     // kb_scan threads
constexpr int SCH = (SM + SCT - 1) / SCT;     // 20 per-thread chunk
constexpr int BND_GRID = N_B / 8;             // 250 boundary blocks

using short8 = __attribute__((ext_vector_type(8))) short;
using f32x16 = __attribute__((ext_vector_type(16))) float;

// softplus via HW exp2/log2: max(x,0) + ln2*log2(1 + 2^(-|x|*log2e)).
__device__ __forceinline__ float softplusf(float x) {
  float p = __builtin_amdgcn_exp2f(-fabsf(x) * 1.44269504088896f);
  float r = __builtin_amdgcn_logf(1.0f + p);  // log2(1+p)
  return fmaxf(x, 0.0f) + r * 0.693147180559945f;
}
__device__ __forceinline__ float b2f(ushort u) {
  return __uint_as_float((uint)u << 16);
}
__device__ __forceinline__ ushort f2b(float f) {
  __hip_bfloat16 h = __float2bfloat16(f);  // RNE
  return *reinterpret_cast<ushort*>(&h);
}
// async global->LDS, 16B per lane; LDS dest = wave-uniform base + lane*16.
__device__ __forceinline__ void gl_lds16(const void* g, void* l) {
  __builtin_amdgcn_global_load_lds(
      (const __attribute__((address_space(1))) void*)g,
      (__attribute__((address_space(3))) void*)l, 16, 0, 0);
}
__device__ __forceinline__ int edge_dst(const int* ei, const int* eb, int e) {
  return (e < E_I) ? ei[E_I + e] : eb[E_B + (e - E_I)];
}
__device__ __forceinline__ int edge_src(const int* ei, const int* eb, int e) {
  return (e < E_I) ? ei[e] : eb[e - E_I];
}

// ---------------- CSR build: two-level bucket, LDS-only atomics ------------
__global__ void kb_hist(const int* __restrict__ ei, const int* __restrict__ eb,
                        int* __restrict__ bh) {
  __shared__ int h[NBIN];
  int t = threadIdx.x;
  for (int i = t; i < NBIN; i += 256) h[i] = 0;
  __syncthreads();
  int base = blockIdx.x * EPB;
  for (int i = t; i < EPB; i += 256) {
    int e = base + i;
    if (e < E_T) atomicAdd(&h[edge_dst(ei, eb, e) >> 10], 1);
  }
  __syncthreads();
  for (int i = t; i < NBIN; i += 256) bh[i * NB + blockIdx.x] = h[i];
}

__global__ __launch_bounds__(SCT) void kb_scan(int* __restrict__ bh) {
  __shared__ int wtot[SCT / 64];
  int t = threadIdx.x;
  int lane = t & 63, wid = t >> 6;
  int base = t * SCH;
  int vals[SCH];
  int s = 0;
#pragma unroll
  for (int i = 0; i < SCH; ++i) {
    int idx = base + i;
    vals[i] = (idx < SM) ? bh[idx] : 0;
    s += vals[i];
  }
  int inc = s;
#pragma unroll
  for (int d = 1; d < 64; d <<= 1) {
    int u = __shfl_up(inc, d, 64);
    if (lane >= d) inc += u;
  }
  if (lane == 63) wtot[wid] = inc;
  __syncthreads();
  int woff = 0;
  for (int i = 0; i < wid; ++i) woff += wtot[i];
  int run = woff + inc - s;
#pragma unroll
  for (int i = 0; i < SCH; ++i) {
    int idx = base + i;
    if (idx < SM) bh[idx] = run;
    run += vals[i];
  }
}

__global__ void kb_scatter(const int* __restrict__ ei, const int* __restrict__ eb,
                           const int* __restrict__ bh, uint* __restrict__ tmp) {
  __shared__ int cur[NBIN];
  int t = threadIdx.x;
  for (int i = t; i < NBIN; i += 256) cur[i] = bh[i * NB + blockIdx.x];
  __syncthreads();
  int base = blockIdx.x * EPB;
  for (int i = t; i < EPB; i += 256) {
    int e = base + i;
    if (e < E_T) {
      int dst = edge_dst(ei, eb, e);
      int src = edge_src(ei, eb, e);
      int pos = atomicAdd(&cur[dst >> 10], 1);
      tmp[pos] = ((uint)dst << 16) | (uint)src;
    }
  }
}

__global__ void kb_nodesort(const int* __restrict__ bh, const uint* __restrict__ tmp,
                            int* __restrict__ offs, ushort* __restrict__ csr,
                            int* __restrict__ zcnt, int* __restrict__ zlist) {
  __shared__ int cnt[1024];
  __shared__ int cur[1024];
  __shared__ int wtot[4];
  int b = blockIdx.x;
  int t = threadIdx.x;
  int lane = t & 63, wid = t >> 6;
  int nb0 = b << 10;
  int nn = min(1024, N_I - nb0);
  int e0 = bh[b * NB];
  int e1 = (b == NBIN - 1) ? E_T : bh[(b + 1) * NB];
#pragma unroll
  for (int i = 0; i < 4; ++i) cnt[t * 4 + i] = 0;
  __syncthreads();
  for (int i = e0 + t; i < e1; i += 256) {
    uint p = tmp[i];
    atomicAdd(&cnt[(int)(p >> 16) - nb0], 1);
  }
  __syncthreads();
  int c4[4];
#pragma unroll
  for (int i = 0; i < 4; ++i) c4[i] = cnt[t * 4 + i];
  int s = c4[0] + c4[1] + c4[2] + c4[3];
  int inc = s;
#pragma unroll
  for (int d = 1; d < 64; d <<= 1) {
    int u = __shfl_up(inc, d, 64);
    if (lane >= d) inc += u;
  }
  if (lane == 63) wtot[wid] = inc;
  __syncthreads();
  int woff = 0;
  for (int i = 0; i < wid; ++i) woff += wtot[i];
  int run = woff + inc - s;
#pragma unroll
  for (int i = 0; i < 4; ++i) {
    int idx = t * 4 + i;
    int v = e0 + run;
    if (idx < nn) {
      offs[nb0 + idx] = v;
      cur[idx] = v;
      if (c4[i] == 0) {
        int p = atomicAdd(zcnt, 1);
        zlist[p] = nb0 + idx;
      }
    }
    run += c4[i];
  }
  if (b == NBIN - 1 && t == 0) offs[N_I] = E_T;
  __syncthreads();
  for (int i = e0 + t; i < e1; i += 256) {
    uint p = tmp[i];
    int pos = atomicAdd(&cur[(int)(p >> 16) - nb0], 1);
    csr[pos] = (ushort)(p & 0xffffu);
  }
}

// ------- fused prep + weight fold (one dispatch, block ranges) -------------
// Blocks [0,CVT_NB): x_int -> bf16-hi. [CVT_NB, +BVT_NB): boundary interp.
// [CVT_NB+BVT_NB, +256): weight folding, 64 blocks per layer.
// M1 = Ws + Wu*Wm_dst, M2 = Wu*Wm_src, c1 = bs+bu+Wu*bm, c0 = bs+bu.
// M1/M2 single-bf16 in MFMA-fragment order:
//   (o,k) -> (((ct*KS + ks)*2 + hi)*32 + l)*8 + e ; WsT fp32 [k][o].
constexpr int CVT_NB = (N_I * 64 / 4 + 255) / 256;  // 3125
constexpr int BVT_NB = (N_B * 64 + 255) / 256;      // 500
struct FoldArgs {
  const float* Wm[4];
  const float* bm[4];
  const float* Ws[4];
  const float* bs[4];
  const float* Wu[4];
  const float* bu[4];
  ushort* M1h[4];
  ushort* M2h[4];
  float* WsT[4];
  float* c1[4];
  float* c0[4];
};
__global__ void k_prepfold(const float* __restrict__ xin, ushort* __restrict__ oh,
                           const float* __restrict__ tptr, const float* __restrict__ ts,
                           const float* __restrict__ BV, float* __restrict__ bvout,
                           ushort* __restrict__ bvouth, FoldArgs fa) {
  int b = blockIdx.x;
  if (b < CVT_NB) {
    int i = b * 256 + threadIdx.x;
    if (i >= N_I * 64 / 4) return;
    float4 v = reinterpret_cast<const float4*>(xin)[i];
    ushort4 h;
    h.x = f2b(v.x); h.y = f2b(v.y); h.z = f2b(v.z); h.w = f2b(v.w);
    reinterpret_cast<ushort4*>(oh)[i] = h;
  } else if (b < CVT_NB + BVT_NB) {
    int idx = (b - CVT_NB) * 256 + threadIdx.x;
    if (idx >= N_B * 64) return;
    float tv = tptr[0];
    int pos = 0;
#pragma unroll
    for (int i = 0; i < 8; ++i) pos += (ts[i] < tv) ? 1 : 0;  // searchsorted
    int il = max(pos - 1, 0), ir = min(pos, 7);
    float tl = ts[il], tr = ts[ir];
    float vl = BV[il * (N_B * 64) + idx];
    float vr = BV[ir * (N_B * 64) + idx];
    bool eq = (tl == tr);
    float denom = eq ? 1.0f : (tr - tl);
    float v = eq ? vl : vl + (tv - tl) * (vr - vl) / denom;
    bvout[idx] = v;
    bvouth[idx] = f2b(v);
  } else {
    int f = b - (CVT_NB + BVT_NB);
    int L = f >> 6;
    int d = (L == 0) ? 64 : 128;
    int so = (L == 3) ? 64 : 128;
    int idx = (f & 63) * 256 + threadIdx.x;
    if (idx < d * so) {
      int o = idx % so, k = idx / so;
      const float* wu = fa.Wu[L] + o * 128;
      const float* Wm = fa.Wm[L];
      float s1 = 0.f, s2 = 0.f;
      int tw = 2 * d;
      for (int j = 0; j < 128; ++j) {
        float u = wu[j];
        s1 = fmaf(u, Wm[j * tw + d + k], s1);
        s2 = fmaf(u, Wm[j * tw + k], s2);
      }
      float wsv = fa.Ws[L][o * d + k];
      int KSr = d >> 4;
      int fo = ((((o >> 5) * KSr + (k >> 4)) * 2 + ((k >> 3) & 1)) * 32 + (o & 31)) * 8 +
               (k & 7);
      fa.M1h[L][fo] = f2b(wsv + s1);
      fa.M2h[L][fo] = f2b(s2);
      fa.WsT[L][k * so + o] = wsv;
    }
    if (idx < so) {
      float s = 0.f;
      for (int j = 0; j < 128; ++j) s = fmaf(fa.Wu[L][idx * 128 + j], fa.bm[L][j], s);
      fa.c1[L][idx] = fa.bs[L][idx] + fa.bu[L][idx] + s;
      fa.c0[L][idx] = fa.bs[L][idx] + fa.bu[L][idx];
    }
  }
}

// ---------------- scatter-mean of bf16-hi features (wave per node) ---------
// Xall holds interior rows 0..N_I-1 AND boundary rows N_I.. -> one base.
// Per 64-edge chunk: one coalesced csr read broadcast via __shfl; all edges
// in 16-deep predicated groups (always issue 16 loads — lane-0 fallback row
// is L1-hot; discard extras with wave-uniform predicates). fp32 accumulate.
template <int D>
__global__ void k_agg(const ushort* __restrict__ Xall, const ushort* __restrict__ csr,
                      const int* __restrict__ offs, ushort* __restrict__ Smh) {
  int v = blockIdx.x * 4 + (threadIdx.x >> 6);
  if (v >= N_I) return;
  int lane = threadIdx.x & 63;
  int o0 = offs[v], o1 = offs[v + 1];
  float a0 = 0.f, a1 = 0.f;
  for (int base = o0; base < o1; base += 64) {
    int n = min(64, o1 - base);
    int idx = (lane < n) ? (int)csr[base + lane] : 0;  // coalesced, 1 load
    for (int j = 0; j < n; j += 16) {
      uint u[16];
      ushort w[16];
#pragma unroll
      for (int q = 0; q < 16; ++q) {
        int s = __shfl(idx, j + q, 64);  // row 0 fallback past n — safe
        const ushort* f = Xall + (size_t)s * D;
        if (D == 128)
          u[q] = *reinterpret_cast<const uint*>(f + lane * 2);
        else
          w[q] = f[lane];
      }
#pragma unroll
      for (int q = 0; q < 16; ++q) {
        if (j + q < n) {  // wave-uniform predicate
          if (D == 128) {
            a0 += __uint_as_float(u[q] << 16);
            a1 += __uint_as_float(u[q] & 0xffff0000u);
          } else {
            a0 += b2f(w[q]);
          }
        }
      }
    }
  }
  float inv = 1.0f / (float)max(o1 - o0, 1);
  float m0 = a0 * inv;
  if (D == 128) {
    float m1 = a1 * inv;
    reinterpret_cast<uint*>(Smh + (size_t)v * D)[lane] =
        (uint)f2b(m0) | ((uint)f2b(m1) << 16);
  } else {
    Smh[(size_t)v * D + lane] = f2b(m0);
  }
}

// ---------------- node update GEMM: Y = act(X*M1^T + Sm*M2^T + c1) ---------
// ONE 32-row tile per block (grid = NTILES). Single-bf16 weights resident;
// A-tiles LDS-staged via global_load_lds w=16, XOR-swizzled source.
// mfma_f32_32x32x16_bf16: A row=lane&31, k=(lane>>5)*8+e; B col=lane&31;
// C/D col=lane&31, row=(r&3)+8*(r>>2)+4*(lane>>5)   [m74/m101]
template <int D, int SO, bool ACT>
__global__ __launch_bounds__(64 * (SO / 32), 2) void k_mm(
    const ushort* __restrict__ Xh, const ushort* __restrict__ Sh,
    const ushort* __restrict__ M1h, const ushort* __restrict__ M2h,
    const float* __restrict__ c1, ushort* __restrict__ Yh,
    float* __restrict__ Yf) {
  constexpr int KS = D / 16;        // MFMA K-steps
  constexpr int CR = D / 8;         // 16B chunks per row
  constexpr int TC = 32 * CR;       // chunks per 32-row tile
  constexpr int W = SO / 32;        // waves per block
  constexpr int CPW = TC / (64 * W);  // gl_lds calls per wave per array
  __shared__ ushort ldsX[32 * D];
  __shared__ ushort ldsS[32 * D];
  int tid = threadIdx.x;
  int wid = tid >> 6, lane = tid & 63;
  int l31 = lane & 31, hi5 = lane >> 5;
  int col = wid * 32 + l31;
  int rt = blockIdx.x;
  // Issue async stage first so it overlaps the weight loads below.
#pragma unroll
  for (int i = 0; i < CPW; ++i) {
    int q0 = (i * W + wid) * 64;   // wave-uniform chunk base
    int q = q0 + lane;             // this lane's chunk
    int r = q / CR, cp = q % CR;
    int cs = cp ^ (r & 7);         // pre-swizzled source chunk
    int rg = min(rt * 32 + r, N_I - 1);
    gl_lds16(Xh + (size_t)rg * D + cs * 8, &ldsX[q0 * 8]);
    gl_lds16(Sh + (size_t)rg * D + cs * 8, &ldsS[q0 * 8]);
  }
  // Fragment-order weight loads: per-lane 16B contiguous, wave-coalesced.
  short8 w1h[KS], w2h[KS];
#pragma unroll
  for (int ks = 0; ks < KS; ++ks) {
    size_t fo = (size_t)(((wid * KS + ks) * 2 + hi5) * 32 + l31) * 8;
    w1h[ks] = *reinterpret_cast<const short8*>(M1h + fo);
    w2h[ks] = *reinterpret_cast<const short8*>(M2h + fo);
  }
  float bias = c1[col];
  __syncthreads();  // stage visible to all waves (drains vmcnt)
  f32x16 accA, accB;
#pragma unroll
  for (int r = 0; r < 16; ++r) {
    accA[r] = bias;
    accB[r] = 0.0f;
  }
#pragma unroll
  for (int ks = 0; ks < KS; ++ks) {
    int c = (ks * 2 + hi5) ^ (l31 & 7);  // swizzled chunk
    const short8 xh = *reinterpret_cast<const short8*>(&ldsX[(l31 * CR + c) * 8]);
    const short8 sh = *reinterpret_cast<const short8*>(&ldsS[(l31 * CR + c) * 8]);
    accA = __builtin_amdgcn_mfma_f32_32x32x16_bf16(xh, w1h[ks], accA, 0, 0, 0);
    accB = __builtin_amdgcn_mfma_f32_32x32x16_bf16(sh, w2h[ks], accB, 0, 0, 0);
  }
#pragma unroll
  for (int r = 0; r < 16; ++r) {
    int rit = (r & 3) + 8 * (r >> 2) + 4 * hi5;
    int grow = rt * 32 + rit;
    if (grow < N_I) {
      float v = accA[r] + accB[r];
      if (ACT) {
        v = softplusf(v);
        Yh[(size_t)grow * SO + col] = f2b(v);
      } else {
        Yf[(size_t)grow * SO + col] = v;
      }
    }
  }
}

// ------- boundary update + deg==0 fixup (merged, one dispatch) -------------
template <int D, int SO, bool ACT>
__global__ void k_bndfix(const float* __restrict__ BVin, const float* __restrict__ WsT,
                         const float* __restrict__ bs, float* __restrict__ out,
                         ushort* __restrict__ outh, const int* __restrict__ zcnt,
                         const int* __restrict__ zlist, const ushort* __restrict__ Xh,
                         const float* __restrict__ c0, ushort* __restrict__ Yh,
                         float* __restrict__ Yf) {
  int t = threadIdx.x;
  if (blockIdx.x >= BND_GRID) {  // fixup block (zcnt ~ 0 rows)
    int nz = zcnt[0];
    int o = t;
    if (o >= SO) return;
    for (int i = 0; i < nz; ++i) {
      int v = zlist[i];
      float s = c0[o];
      for (int k = 0; k < D; ++k)
        s = fmaf(WsT[k * SO + o], b2f(Xh[(size_t)v * D + k]), s);
      if (ACT) {
        s = softplusf(s);
        if (Yh) Yh[(size_t)v * SO + o] = f2b(s);
      } else if (Yf) {
        Yf[(size_t)v * SO + o] = s;
      }
    }
    return;
  }
  constexpr int TPN = SO / 4;
  constexpr int NPB = 256 / TPN;
  __shared__ float lx[NPB * D];
  int base = blockIdx.x * NPB;
  for (int i = t; i < NPB * D; i += 256) lx[i] = BVin[(size_t)base * D + i];
  __syncthreads();
  int g = t / TPN;
  int o = (t % TPN) * 4;
  int v = base + g;
  float4 acc = make_float4(bs[o], bs[o + 1], bs[o + 2], bs[o + 3]);
  const float* xr = lx + g * D;
  const float4* W4 = reinterpret_cast<const float4*>(WsT);
#pragma unroll 8
  for (int k = 0; k < D; ++k) {
    float4 w = W4[k * (SO / 4) + (o >> 2)];
    float xv = xr[k];
    acc.x = fmaf(xv, w.x, acc.x);
    acc.y = fmaf(xv, w.y, acc.y);
    acc.z = fmaf(xv, w.z, acc.z);
    acc.w = fmaf(xv, w.w, acc.w);
  }
  float4 ov;
  ov.x = softplusf(acc.x);
  ov.y = softplusf(acc.y);
  ov.z = softplusf(acc.z);
  ov.w = softplusf(acc.w);
  reinterpret_cast<float4*>(out + (size_t)v * SO)[o >> 2] = ov;
  ushort4 oh;
  oh.x = f2b(ov.x); oh.y = f2b(ov.y); oh.z = f2b(ov.z); oh.w = f2b(ov.w);
  reinterpret_cast<ushort4*>(outh + (size_t)v * SO)[o >> 2] = oh;
}

// Standalone fixup for layer 4 (no boundary update after the last layer).
template <int D, int SO>
__global__ void k_fix4(const int* __restrict__ zcnt, const int* __restrict__ zlist,
                       const ushort* __restrict__ Xh, const float* __restrict__ WsT,
                       const float* __restrict__ c0, float* __restrict__ Yf) {
  int nz = zcnt[0];
  int o = threadIdx.x;
  if (o >= SO) return;
  for (int i = 0; i < nz; ++i) {
    int v = zlist[i];
    float s = c0[o];
    for (int k = 0; k < D; ++k)
      s = fmaf(WsT[k * SO + o], b2f(Xh[(size_t)v * D + k]), s);
    Yf[(size_t)v * SO + o] = s;
  }
}

extern "C" void kernel_launch(void* const* d_in, const int* in_sizes, int n_in,
                              void* d_out, int out_size, void* d_ws, size_t ws_size,
                              hipStream_t stream) {
  const float* t_in = (const float*)d_in[0];
  const float* x_int = (const float*)d_in[1];
  const float* bvals = (const float*)d_in[2];
  const int* ei = (const int*)d_in[3];
  const int* eb = (const int*)d_in[4];
  const float* ts = (const float*)d_in[5];
  const float* W[4][6];
  for (int l = 0; l < 4; ++l)
    for (int j = 0; j < 6; ++j) W[l][j] = (const float*)d_in[6 + l * 6 + j];
  // j: 0=Wm 1=bm 2=Ws 3=bs 4=Wu 5=bu

  char* ws = (char*)d_ws;
  size_t off = 0;
  auto alloc = [&](size_t bytes) {
    void* p = ws + off;
    off = (off + bytes + 255) & ~(size_t)255;
    return p;
  };
  int* bh = (int*)alloc((size_t)SM * 4);
  uint* etmp = (uint*)alloc((size_t)E_T * 4);
  int* offs = (int*)alloc((N_I + 1) * 4);
  ushort* csr = (ushort*)alloc((size_t)E_T * 2);
  int* zcnt = (int*)alloc(4);
  int* zlist = (int*)alloc(N_I * 4);
  // Activation ping-pong, bf16 hi; rows N_I.. hold the boundary tail.
  ushort* Ah = (ushort*)alloc((size_t)(N_I + N_B) * 128 * 2);
  ushort* Bh = (ushort*)alloc((size_t)(N_I + N_B) * 128 * 2);
  ushort* Smh = (ushort*)alloc((size_t)N_I * 128 * 2);
  float* bv1 = (float*)alloc((size_t)N_B * 64 * 4);
  float* bv2 = (float*)alloc((size_t)N_B * 128 * 4);
  float* bv3 = (float*)alloc((size_t)N_B * 128 * 4);
  float* bv4 = (float*)alloc((size_t)N_B * 128 * 4);
  FoldArgs fa;
  for (int l = 0; l < 4; ++l) {
    fa.Wm[l] = W[l][0]; fa.bm[l] = W[l][1]; fa.Ws[l] = W[l][2];
    fa.bs[l] = W[l][3]; fa.Wu[l] = W[l][4]; fa.bu[l] = W[l][5];
    fa.M1h[l] = (ushort*)alloc(16384 * 2);
    fa.M2h[l] = (ushort*)alloc(16384 * 2);
    fa.WsT[l] = (float*)alloc(16384 * 4);
    fa.c1[l] = (float*)alloc(128 * 4);
    fa.c0[l] = (float*)alloc(128 * 4);
  }
  (void)ws_size; (void)in_sizes; (void)n_in; (void)out_size;

  hipMemsetAsync(zcnt, 0, 4, stream);
  // CSR build: hist -> scan -> bucket scatter -> per-bin node sort (+zlist).
  kb_hist<<<NB, 256, 0, stream>>>(ei, eb, bh);
  kb_scan<<<1, SCT, 0, stream>>>(bh);
  kb_scatter<<<NB, 256, 0, stream>>>(ei, eb, bh, etmp);
  kb_nodesort<<<NBIN, 256, 0, stream>>>(bh, etmp, offs, csr, zcnt, zlist);
  // Fused: x->bf16 | boundary interp | weight folds (one dispatch).
  k_prepfold<<<CVT_NB + BVT_NB + 256, 256, 0, stream>>>(
      x_int, Ah, t_in, ts, bvals, bv1, Ah + (size_t)N_I * 64, fa);

  // Layer 1: D=64 -> 128   (reads Ah [N_I+N_B][64], writes Bh [..][128])
  k_agg<64><<<N_I / 4, 256, 0, stream>>>(Ah, csr, offs, Smh);
  k_mm<64, 128, true><<<NTILES, 256, 0, stream>>>(Ah, Smh, fa.M1h[0], fa.M2h[0],
                                                  fa.c1[0], Bh, nullptr);
  k_bndfix<64, 128, true><<<BND_GRID + 1, 256, 0, stream>>>(
      bv1, fa.WsT[0], W[0][3], bv2, Bh + (size_t)N_I * 128, zcnt, zlist, Ah,
      fa.c0[0], Bh, nullptr);

  // Layer 2: 128 -> 128    (reads Bh, overwrites Ah)
  k_agg<128><<<N_I / 4, 256, 0, stream>>>(Bh, csr, offs, Smh);
  k_mm<128, 128, true><<<NTILES, 256, 0, stream>>>(Bh, Smh, fa.M1h[1], fa.M2h[1],
                                                   fa.c1[1], Ah, nullptr);
  k_bndfix<128, 128, true><<<BND_GRID + 1, 256, 0, stream>>>(
      bv2, fa.WsT[1], W[1][3], bv3, Ah + (size_t)N_I * 128, zcnt, zlist, Bh,
      fa.c0[1], Ah, nullptr);

  // Layer 3: 128 -> 128    (reads Ah, writes Bh)
  k_agg<128><<<N_I / 4, 256, 0, stream>>>(Ah, csr, offs, Smh);
  k_mm<128, 128, true><<<NTILES, 256, 0, stream>>>(Ah, Smh, fa.M1h[2], fa.M2h[2],
                                                   fa.c1[2], Bh, nullptr);
  k_bndfix<128, 128, true><<<BND_GRID + 1, 256, 0, stream>>>(
      bv3, fa.WsT[2], W[2][3], bv4, Bh + (size_t)N_I * 128, zcnt, zlist, Ah,
      fa.c0[2], Bh, nullptr);

  // Layer 4: 128 -> 64, no activation, fp32 straight to d_out
  k_agg<128><<<N_I / 4, 256, 0, stream>>>(Bh, csr, offs, Smh);
  k_mm<128, 64, false><<<NTILES, 128, 0, stream>>>(Bh, Smh, fa.M1h[3], fa.M2h[3],
                                                   fa.c1[3], nullptr, (float*)d_out);
  k_fix4<128, 64><<<1, 128, 0, stream>>>(zcnt, zlist, Bh, fa.WsT[3], fa.c0[3],
                                         (float*)d_out);
}

// Round 17
// 254.610 us; speedup vs baseline: 1.0311x; 1.0311x over previous
//
#include <hip/hip_runtime.h>
#include <hip/hip_bf16.h>
#include <math.h>

// Problem constants (fixed by the reference).
constexpr int N_I = 50000;   // interior nodes
constexpr int N_B = 2000;    // boundary nodes
constexpr int E_I = 800000;  // interior edges
constexpr int E_B = 16000;   // boundary edges
constexpr int E_T = E_I + E_B;
constexpr int NTILES = (N_I + 31) / 32;       // 1563 row-tiles
// CSR bucket build
constexpr int NBIN = (N_I + 1023) / 1024;     // 49 bins of 1024 nodes
constexpr int EPB = 2048;                     // edges per hist/scatter block
constexpr int NB = (E_T + EPB - 1) / EPB;     // 399 blocks
constexpr int SM = NBIN * NB;                 // 19551 scan entries
constexpr int SCT = 1024;                     // kb_scan threads
constexpr int SCH = (SM + SCT - 1) / SCT;     // 20 per-thread chunk
constexpr int BND_GRID = N_B / 8;             // 250 boundary blocks

using short8 = __attribute__((ext_vector_type(8))) short;
using f32x16 = __attribute__((ext_vector_type(16))) float;

// softplus via HW exp2/log2: max(x,0) + ln2*log2(1 + 2^(-|x|*log2e)).
__device__ __forceinline__ float softplusf(float x) {
  float p = __builtin_amdgcn_exp2f(-fabsf(x) * 1.44269504088896f);
  float r = __builtin_amdgcn_logf(1.0f + p);  // log2(1+p)
  return fmaxf(x, 0.0f) + r * 0.693147180559945f;
}
__device__ __forceinline__ float b2f(ushort u) {
  return __uint_as_float((uint)u << 16);
}
__device__ __forceinline__ ushort f2b(float f) {
  __hip_bfloat16 h = __float2bfloat16(f);  // RNE
  return *reinterpret_cast<ushort*>(&h);
}
// async global->LDS, 16B per lane; LDS dest = wave-uniform base + lane*16.
__device__ __forceinline__ void gl_lds16(const void* g, void* l) {
  __builtin_amdgcn_global_load_lds(
      (const __attribute__((address_space(1))) void*)g,
      (__attribute__((address_space(3))) void*)l, 16, 0, 0);
}
__device__ __forceinline__ int edge_dst(const int* ei, const int* eb, int e) {
  return (e < E_I) ? ei[E_I + e] : eb[E_B + (e - E_I)];
}
__device__ __forceinline__ int edge_src(const int* ei, const int* eb, int e) {
  return (e < E_I) ? ei[e] : eb[e - E_I];
}

// ---------------- CSR build: two-level bucket, LDS-only atomics ------------
__global__ void kb_hist(const int* __restrict__ ei, const int* __restrict__ eb,
                        int* __restrict__ bh) {
  __shared__ int h[NBIN];
  int t = threadIdx.x;
  for (int i = t; i < NBIN; i += 256) h[i] = 0;
  __syncthreads();
  int base = blockIdx.x * EPB;
  for (int i = t; i < EPB; i += 256) {
    int e = base + i;
    if (e < E_T) atomicAdd(&h[edge_dst(ei, eb, e) >> 10], 1);
  }
  __syncthreads();
  for (int i = t; i < NBIN; i += 256) bh[i * NB + blockIdx.x] = h[i];
}

__global__ __launch_bounds__(SCT) void kb_scan(int* __restrict__ bh) {
  __shared__ int wtot[SCT / 64];
  int t = threadIdx.x;
  int lane = t & 63, wid = t >> 6;
  int base = t * SCH;
  int vals[SCH];
  int s = 0;
#pragma unroll
  for (int i = 0; i < SCH; ++i) {
    int idx = base + i;
    vals[i] = (idx < SM) ? bh[idx] : 0;
    s += vals[i];
  }
  int inc = s;
#pragma unroll
  for (int d = 1; d < 64; d <<= 1) {
    int u = __shfl_up(inc, d, 64);
    if (lane >= d) inc += u;
  }
  if (lane == 63) wtot[wid] = inc;
  __syncthreads();
  int woff = 0;
  for (int i = 0; i < wid; ++i) woff += wtot[i];
  int run = woff + inc - s;
#pragma unroll
  for (int i = 0; i < SCH; ++i) {
    int idx = base + i;
    if (idx < SM) bh[idx] = run;
    run += vals[i];
  }
}

__global__ void kb_scatter(const int* __restrict__ ei, const int* __restrict__ eb,
                           const int* __restrict__ bh, uint* __restrict__ tmp) {
  __shared__ int cur[NBIN];
  int t = threadIdx.x;
  for (int i = t; i < NBIN; i += 256) cur[i] = bh[i * NB + blockIdx.x];
  __syncthreads();
  int base = blockIdx.x * EPB;
  for (int i = t; i < EPB; i += 256) {
    int e = base + i;
    if (e < E_T) {
      int dst = edge_dst(ei, eb, e);
      int src = edge_src(ei, eb, e);
      int pos = atomicAdd(&cur[dst >> 10], 1);
      tmp[pos] = ((uint)dst << 16) | (uint)src;
    }
  }
}

__global__ void kb_nodesort(const int* __restrict__ bh, const uint* __restrict__ tmp,
                            int* __restrict__ offs, ushort* __restrict__ csr,
                            int* __restrict__ zcnt, int* __restrict__ zlist) {
  __shared__ int cnt[1024];
  __shared__ int cur[1024];
  __shared__ int wtot[4];
  int b = blockIdx.x;
  int t = threadIdx.x;
  int lane = t & 63, wid = t >> 6;
  int nb0 = b << 10;
  int nn = min(1024, N_I - nb0);
  int e0 = bh[b * NB];
  int e1 = (b == NBIN - 1) ? E_T : bh[(b + 1) * NB];
#pragma unroll
  for (int i = 0; i < 4; ++i) cnt[t * 4 + i] = 0;
  __syncthreads();
  for (int i = e0 + t; i < e1; i += 256) {
    uint p = tmp[i];
    atomicAdd(&cnt[(int)(p >> 16) - nb0], 1);
  }
  __syncthreads();
  int c4[4];
#pragma unroll
  for (int i = 0; i < 4; ++i) c4[i] = cnt[t * 4 + i];
  int s = c4[0] + c4[1] + c4[2] + c4[3];
  int inc = s;
#pragma unroll
  for (int d = 1; d < 64; d <<= 1) {
    int u = __shfl_up(inc, d, 64);
    if (lane >= d) inc += u;
  }
  if (lane == 63) wtot[wid] = inc;
  __syncthreads();
  int woff = 0;
  for (int i = 0; i < wid; ++i) woff += wtot[i];
  int run = woff + inc - s;
#pragma unroll
  for (int i = 0; i < 4; ++i) {
    int idx = t * 4 + i;
    int v = e0 + run;
    if (idx < nn) {
      offs[nb0 + idx] = v;
      cur[idx] = v;
      if (c4[i] == 0) {
        int p = atomicAdd(zcnt, 1);
        zlist[p] = nb0 + idx;
      }
    }
    run += c4[i];
  }
  if (b == NBIN - 1 && t == 0) offs[N_I] = E_T;
  __syncthreads();
  for (int i = e0 + t; i < e1; i += 256) {
    uint p = tmp[i];
    int pos = atomicAdd(&cur[(int)(p >> 16) - nb0], 1);
    csr[pos] = (ushort)(p & 0xffffu);
  }
}

// ------- fused prep + weight fold (one dispatch, block ranges) -------------
constexpr int CVT_NB = (N_I * 64 / 4 + 255) / 256;  // 3125
constexpr int BVT_NB = (N_B * 64 + 255) / 256;      // 500
struct FoldArgs {
  const float* Wm[4];
  const float* bm[4];
  const float* Ws[4];
  const float* bs[4];
  const float* Wu[4];
  const float* bu[4];
  ushort* M1h[4];
  ushort* M2h[4];
  float* WsT[4];
  float* c1[4];
  float* c0[4];
};
__global__ void k_prepfold(const float* __restrict__ xin, ushort* __restrict__ oh,
                           const float* __restrict__ tptr, const float* __restrict__ ts,
                           const float* __restrict__ BV, float* __restrict__ bvout,
                           ushort* __restrict__ bvouth, FoldArgs fa) {
  int b = blockIdx.x;
  if (b < CVT_NB) {
    int i = b * 256 + threadIdx.x;
    if (i >= N_I * 64 / 4) return;
    float4 v = reinterpret_cast<const float4*>(xin)[i];
    ushort4 h;
    h.x = f2b(v.x); h.y = f2b(v.y); h.z = f2b(v.z); h.w = f2b(v.w);
    reinterpret_cast<ushort4*>(oh)[i] = h;
  } else if (b < CVT_NB + BVT_NB) {
    int idx = (b - CVT_NB) * 256 + threadIdx.x;
    if (idx >= N_B * 64) return;
    float tv = tptr[0];
    int pos = 0;
#pragma unroll
    for (int i = 0; i < 8; ++i) pos += (ts[i] < tv) ? 1 : 0;  // searchsorted
    int il = max(pos - 1, 0), ir = min(pos, 7);
    float tl = ts[il], tr = ts[ir];
    float vl = BV[il * (N_B * 64) + idx];
    float vr = BV[ir * (N_B * 64) + idx];
    bool eq = (tl == tr);
    float denom = eq ? 1.0f : (tr - tl);
    float v = eq ? vl : vl + (tv - tl) * (vr - vl) / denom;
    bvout[idx] = v;
    bvouth[idx] = f2b(v);
  } else {
    int f = b - (CVT_NB + BVT_NB);
    int L = f >> 6;
    int d = (L == 0) ? 64 : 128;
    int so = (L == 3) ? 64 : 128;
    int idx = (f & 63) * 256 + threadIdx.x;
    if (idx < d * so) {
      int o = idx % so, k = idx / so;
      const float* wu = fa.Wu[L] + o * 128;
      const float* Wm = fa.Wm[L];
      float s1 = 0.f, s2 = 0.f;
      int tw = 2 * d;
      for (int j = 0; j < 128; ++j) {
        float u = wu[j];
        s1 = fmaf(u, Wm[j * tw + d + k], s1);
        s2 = fmaf(u, Wm[j * tw + k], s2);
      }
      float wsv = fa.Ws[L][o * d + k];
      int KSr = d >> 4;
      int fo = ((((o >> 5) * KSr + (k >> 4)) * 2 + ((k >> 3) & 1)) * 32 + (o & 31)) * 8 +
               (k & 7);
      fa.M1h[L][fo] = f2b(wsv + s1);
      fa.M2h[L][fo] = f2b(s2);
      fa.WsT[L][k * so + o] = wsv;
    }
    if (idx < so) {
      float s = 0.f;
      for (int j = 0; j < 128; ++j) s = fmaf(fa.Wu[L][idx * 128 + j], fa.bm[L][j], s);
      fa.c1[L][idx] = fa.bs[L][idx] + fa.bu[L][idx] + s;
      fa.c0[L][idx] = fa.bs[L][idx] + fa.bu[L][idx];
    }
  }
}

// ---------------- scatter-mean of bf16-hi features (wave per node) ---------
// Xall holds interior rows 0..N_I-1 AND boundary rows N_I.. -> one base.
// Per 64-edge chunk: one coalesced csr read broadcast via __shfl; all edges
// in 8-deep predicated groups (r15 config — best measured; 16-deep neutral).
template <int D>
__global__ void k_agg(const ushort* __restrict__ Xall, const ushort* __restrict__ csr,
                      const int* __restrict__ offs, ushort* __restrict__ Smh) {
  int v = blockIdx.x * 4 + (threadIdx.x >> 6);
  if (v >= N_I) return;
  int lane = threadIdx.x & 63;
  int o0 = offs[v], o1 = offs[v + 1];
  float a0 = 0.f, a1 = 0.f;
  for (int base = o0; base < o1; base += 64) {
    int n = min(64, o1 - base);
    int idx = (lane < n) ? (int)csr[base + lane] : 0;  // coalesced, 1 load
    for (int j = 0; j < n; j += 8) {
      uint u[8];
      ushort w[8];
#pragma unroll
      for (int q = 0; q < 8; ++q) {
        int s = __shfl(idx, j + q, 64);  // row 0 fallback past n — safe
        const ushort* f = Xall + (size_t)s * D;
        if (D == 128)
          u[q] = *reinterpret_cast<const uint*>(f + lane * 2);
        else
          w[q] = f[lane];
      }
#pragma unroll
      for (int q = 0; q < 8; ++q) {
        if (j + q < n) {  // wave-uniform predicate
          if (D == 128) {
            a0 += __uint_as_float(u[q] << 16);
            a1 += __uint_as_float(u[q] & 0xffff0000u);
          } else {
            a0 += b2f(w[q]);
          }
        }
      }
    }
  }
  float inv = 1.0f / (float)max(o1 - o0, 1);
  float m0 = a0 * inv;
  if (D == 128) {
    float m1 = a1 * inv;
    reinterpret_cast<uint*>(Smh + (size_t)v * D)[lane] =
        (uint)f2b(m0) | ((uint)f2b(m1) << 16);
  } else {
    Smh[(size_t)v * D + lane] = f2b(m0);
  }
}

// ------- fused node GEMM + boundary update + deg==0 fixup ------------------
// Blocks [0,NTILES): one 32-row GEMM tile each (single-bf16 weights resident,
//   LDS-staged A via global_load_lds w=16 with XOR-swizzled source).
// Blocks [NTILES, NTILES+BND_GRID) when BND: boundary rows (8/block), reusing
//   ldsX as fp32 staging. Last block: deg==0 fixup (zcnt ~ 0 rows).
// mfma_f32_32x32x16_bf16: A row=lane&31, k=(lane>>5)*8+e; B col=lane&31;
// C/D col=lane&31, row=(r&3)+8*(r>>2)+4*(lane>>5)   [m74/m101]
template <int D, int SO, bool ACT, bool BND>
__global__ __launch_bounds__(64 * (SO / 32), 2) void k_mm(
    const ushort* __restrict__ Xh, const ushort* __restrict__ Sh,
    const ushort* __restrict__ M1h, const ushort* __restrict__ M2h,
    const float* __restrict__ c1, ushort* __restrict__ Yh, float* __restrict__ Yf,
    const float* __restrict__ BVin, const float* __restrict__ WsT,
    const float* __restrict__ bs, float* __restrict__ bvout,
    ushort* __restrict__ bvouth, const int* __restrict__ zcnt,
    const int* __restrict__ zlist, const float* __restrict__ c0) {
  constexpr int KS = D / 16;          // MFMA K-steps
  constexpr int CR = D / 8;           // 16B chunks per row
  constexpr int TC = 32 * CR;         // chunks per 32-row tile
  constexpr int W = SO / 32;          // waves per block
  constexpr int CPW = TC / (64 * W);  // gl_lds calls per wave per array
  constexpr int NT = 64 * W;          // threads per block
  __shared__ ushort ldsX[32 * D];
  __shared__ ushort ldsS[32 * D];
  int tid = threadIdx.x;
  int rt = blockIdx.x;
  if (rt >= NTILES) {
    int bb = rt - NTILES;
    if (BND && bb < BND_GRID) {
      // ---- boundary update: bv' = softplus(Ws*bv + bs) ----
      constexpr int TPN = SO / 4;
      constexpr int NPB = NT / TPN;
      float* lx = reinterpret_cast<float*>(ldsX);  // NPB*D*4 <= 32*D*2
      int base = bb * NPB;
      for (int i = tid; i < NPB * D; i += NT) lx[i] = BVin[(size_t)base * D + i];
      __syncthreads();
      int g = tid / TPN;
      int o = (tid % TPN) * 4;
      int v = base + g;
      float4 acc = make_float4(bs[o], bs[o + 1], bs[o + 2], bs[o + 3]);
      const float* xr = lx + g * D;
      const float4* W4 = reinterpret_cast<const float4*>(WsT);
#pragma unroll 8
      for (int k = 0; k < D; ++k) {
        float4 w = W4[k * (SO / 4) + (o >> 2)];
        float xv = xr[k];
        acc.x = fmaf(xv, w.x, acc.x);
        acc.y = fmaf(xv, w.y, acc.y);
        acc.z = fmaf(xv, w.z, acc.z);
        acc.w = fmaf(xv, w.w, acc.w);
      }
      float4 ov;
      ov.x = softplusf(acc.x);
      ov.y = softplusf(acc.y);
      ov.z = softplusf(acc.z);
      ov.w = softplusf(acc.w);
      reinterpret_cast<float4*>(bvout + (size_t)v * SO)[o >> 2] = ov;
      ushort4 oh;
      oh.x = f2b(ov.x); oh.y = f2b(ov.y); oh.z = f2b(ov.z); oh.w = f2b(ov.w);
      reinterpret_cast<ushort4*>(bvouth + (size_t)v * SO)[o >> 2] = oh;
    } else {
      // ---- deg==0 fixup: y = act(Ws*x + c0) ----
      int nz = zcnt[0];
      int o = tid;
      if (o >= SO) return;
      for (int i = 0; i < nz; ++i) {
        int v = zlist[i];
        float s = c0[o];
        for (int k = 0; k < D; ++k)
          s = fmaf(WsT[k * SO + o], b2f(Xh[(size_t)v * D + k]), s);
        if (ACT) {
          s = softplusf(s);
          Yh[(size_t)v * SO + o] = f2b(s);
        } else {
          Yf[(size_t)v * SO + o] = s;
        }
      }
    }
    return;
  }
  int wid = tid >> 6, lane = tid & 63;
  int l31 = lane & 31, hi5 = lane >> 5;
  int col = wid * 32 + l31;
  // Issue async stage first so it overlaps the weight loads below.
#pragma unroll
  for (int i = 0; i < CPW; ++i) {
    int q0 = (i * W + wid) * 64;   // wave-uniform chunk base
    int q = q0 + lane;             // this lane's chunk
    int r = q / CR, cp = q % CR;
    int cs = cp ^ (r & 7);         // pre-swizzled source chunk
    int rg = min(rt * 32 + r, N_I - 1);
    gl_lds16(Xh + (size_t)rg * D + cs * 8, &ldsX[q0 * 8]);
    gl_lds16(Sh + (size_t)rg * D + cs * 8, &ldsS[q0 * 8]);
  }
  // Fragment-order weight loads: per-lane 16B contiguous, wave-coalesced.
  short8 w1h[KS], w2h[KS];
#pragma unroll
  for (int ks = 0; ks < KS; ++ks) {
    size_t fo = (size_t)(((wid * KS + ks) * 2 + hi5) * 32 + l31) * 8;
    w1h[ks] = *reinterpret_cast<const short8*>(M1h + fo);
    w2h[ks] = *reinterpret_cast<const short8*>(M2h + fo);
  }
  float bias = c1[col];
  __syncthreads();  // stage visible to all waves (drains vmcnt)
  f32x16 accA, accB;
#pragma unroll
  for (int r = 0; r < 16; ++r) {
    accA[r] = bias;
    accB[r] = 0.0f;
  }
#pragma unroll
  for (int ks = 0; ks < KS; ++ks) {
    int c = (ks * 2 + hi5) ^ (l31 & 7);  // swizzled chunk
    const short8 xh = *reinterpret_cast<const short8*>(&ldsX[(l31 * CR + c) * 8]);
    const short8 sh = *reinterpret_cast<const short8*>(&ldsS[(l31 * CR + c) * 8]);
    accA = __builtin_amdgcn_mfma_f32_32x32x16_bf16(xh, w1h[ks], accA, 0, 0, 0);
    accB = __builtin_amdgcn_mfma_f32_32x32x16_bf16(sh, w2h[ks], accB, 0, 0, 0);
  }
#pragma unroll
  for (int r = 0; r < 16; ++r) {
    int rit = (r & 3) + 8 * (r >> 2) + 4 * hi5;
    int grow = rt * 32 + rit;
    if (grow < N_I) {
      float v = accA[r] + accB[r];
      if (ACT) {
        v = softplusf(v);
        Yh[(size_t)grow * SO + col] = f2b(v);
      } else {
        Yf[(size_t)grow * SO + col] = v;
      }
    }
  }
}

extern "C" void kernel_launch(void* const* d_in, const int* in_sizes, int n_in,
                              void* d_out, int out_size, void* d_ws, size_t ws_size,
                              hipStream_t stream) {
  const float* t_in = (const float*)d_in[0];
  const float* x_int = (const float*)d_in[1];
  const float* bvals = (const float*)d_in[2];
  const int* ei = (const int*)d_in[3];
  const int* eb = (const int*)d_in[4];
  const float* ts = (const float*)d_in[5];
  const float* W[4][6];
  for (int l = 0; l < 4; ++l)
    for (int j = 0; j < 6; ++j) W[l][j] = (const float*)d_in[6 + l * 6 + j];
  // j: 0=Wm 1=bm 2=Ws 3=bs 4=Wu 5=bu

  char* ws = (char*)d_ws;
  size_t off = 0;
  auto alloc = [&](size_t bytes) {
    void* p = ws + off;
    off = (off + bytes + 255) & ~(size_t)255;
    return p;
  };
  int* bh = (int*)alloc((size_t)SM * 4);
  uint* etmp = (uint*)alloc((size_t)E_T * 4);
  int* offs = (int*)alloc((N_I + 1) * 4);
  ushort* csr = (ushort*)alloc((size_t)E_T * 2);
  int* zcnt = (int*)alloc(4);
  int* zlist = (int*)alloc(N_I * 4);
  // Activation ping-pong, bf16 hi; rows N_I.. hold the boundary tail.
  ushort* Ah = (ushort*)alloc((size_t)(N_I + N_B) * 128 * 2);
  ushort* Bh = (ushort*)alloc((size_t)(N_I + N_B) * 128 * 2);
  ushort* Smh = (ushort*)alloc((size_t)N_I * 128 * 2);
  float* bv1 = (float*)alloc((size_t)N_B * 64 * 4);
  float* bv2 = (float*)alloc((size_t)N_B * 128 * 4);
  float* bv3 = (float*)alloc((size_t)N_B * 128 * 4);
  float* bv4 = (float*)alloc((size_t)N_B * 128 * 4);
  FoldArgs fa;
  for (int l = 0; l < 4; ++l) {
    fa.Wm[l] = W[l][0]; fa.bm[l] = W[l][1]; fa.Ws[l] = W[l][2];
    fa.bs[l] = W[l][3]; fa.Wu[l] = W[l][4]; fa.bu[l] = W[l][5];
    fa.M1h[l] = (ushort*)alloc(16384 * 2);
    fa.M2h[l] = (ushort*)alloc(16384 * 2);
    fa.WsT[l] = (float*)alloc(16384 * 4);
    fa.c1[l] = (float*)alloc(128 * 4);
    fa.c0[l] = (float*)alloc(128 * 4);
  }
  (void)ws_size; (void)in_sizes; (void)n_in; (void)out_size;

  hipMemsetAsync(zcnt, 0, 4, stream);
  // CSR build: hist -> scan -> bucket scatter -> per-bin node sort (+zlist).
  kb_hist<<<NB, 256, 0, stream>>>(ei, eb, bh);
  kb_scan<<<1, SCT, 0, stream>>>(bh);
  kb_scatter<<<NB, 256, 0, stream>>>(ei, eb, bh, etmp);
  kb_nodesort<<<NBIN, 256, 0, stream>>>(bh, etmp, offs, csr, zcnt, zlist);
  // Fused: x->bf16 | boundary interp | weight folds (one dispatch).
  k_prepfold<<<CVT_NB + BVT_NB + 256, 256, 0, stream>>>(
      x_int, Ah, t_in, ts, bvals, bv1, Ah + (size_t)N_I * 64, fa);

  // Layer 1: D=64 -> 128   (reads Ah [N_I+N_B][64], writes Bh [..][128])
  k_agg<64><<<N_I / 4, 256, 0, stream>>>(Ah, csr, offs, Smh);
  k_mm<64, 128, true, true><<<NTILES + BND_GRID + 1, 256, 0, stream>>>(
      Ah, Smh, fa.M1h[0], fa.M2h[0], fa.c1[0], Bh, nullptr, bv1, fa.WsT[0],
      W[0][3], bv2, Bh + (size_t)N_I * 128, zcnt, zlist, fa.c0[0]);

  // Layer 2: 128 -> 128    (reads Bh, overwrites Ah)
  k_agg<128><<<N_I / 4, 256, 0, stream>>>(Bh, csr, offs, Smh);
  k_mm<128, 128, true, true><<<NTILES + BND_GRID + 1, 256, 0, stream>>>(
      Bh, Smh, fa.M1h[1], fa.M2h[1], fa.c1[1], Ah, nullptr, bv2, fa.WsT[1],
      W[1][3], bv3, Ah + (size_t)N_I * 128, zcnt, zlist, fa.c0[1]);

  // Layer 3: 128 -> 128    (reads Ah, writes Bh)
  k_agg<128><<<N_I / 4, 256, 0, stream>>>(Ah, csr, offs, Smh);
  k_mm<128, 128, true, true><<<NTILES + BND_GRID + 1, 256, 0, stream>>>(
      Ah, Smh, fa.M1h[2], fa.M2h[2], fa.c1[2], Bh, nullptr, bv3, fa.WsT[2],
      W[2][3], bv4, Bh + (size_t)N_I * 128, zcnt, zlist, fa.c0[2]);

  // Layer 4: 128 -> 64, no activation, fp32 to d_out (fixup block appended)
  k_agg<128><<<N_I / 4, 256, 0, stream>>>(Bh, csr, offs, Smh);
  k_mm<128, 64, false, false><<<NTILES + 1, 128, 0, stream>>>(
      Bh, Smh, fa.M1h[3], fa.M2h[3], fa.c1[3], nullptr, (float*)d_out, nullptr,
      fa.WsT[3], nullptr, nullptr, nullptr, zcnt, zlist, fa.c0[3]);
}